// Round 16
// baseline (143.110 us; speedup 1.0000x reference)
//
#include <hip/hip_runtime.h>

#define B 128
#define N 65536
#define D 512
#define K 5
#define M 256              // D * RATIO
#define GPB 256            // gallery rows per block (kernel1)
#define NBLK1 (N / GPB)    // 256 blocks
#define CHR 16             // g-rows per chunk (full D each)
#define NCHK (GPB / CHR)   // 16
#define RSTR 2064          // padded LDS row stride (bytes): 516 dwords ≡ 4 mod 32

typedef __attribute__((ext_vector_type(8))) short short8;
typedef __attribute__((ext_vector_type(4))) float f32x4;
typedef __attribute__((address_space(1))) const unsigned char as1cu8;
typedef __attribute__((address_space(3))) unsigned char as3u8;

// pack two fp32 -> one u32 of 2 bf16 (truncation) via v_perm_b32.
__device__ __forceinline__ unsigned int pack_bf2(float lo, float hi) {
    return __builtin_amdgcn_perm(__float_as_uint(hi), __float_as_uint(lo), 0x07060302u);
}

__device__ __forceinline__ void top5_insert(float v, int gi, float tv[K], int ti[K]) {
    // descending by value, ties broken by lower index (matches lax.top_k)
    if (v > tv[K - 1] || (v == tv[K - 1] && gi < ti[K - 1])) {
        tv[K - 1] = v; ti[K - 1] = gi;
        #pragma unroll
        for (int k = K - 1; k > 0; --k) {
            bool sw = (tv[k] > tv[k - 1]) || (tv[k] == tv[k - 1] && ti[k] < ti[k - 1]);
            if (sw) {
                float fv = tv[k]; tv[k] = tv[k - 1]; tv[k - 1] = fv;
                int fi = ti[k]; ti[k] = ti[k - 1]; ti[k - 1] = fi;
            }
        }
    }
}

// packed-score insert (meta lives in low 8 mantissa bits; candidates distinct)
__device__ __forceinline__ void pk_insert(float sp, float lst[K]) {
    if (sp > lst[K - 1]) {
        lst[K - 1] = sp;
        #pragma unroll
        for (int k = K - 1; k > 0; --k)
            if (lst[k] > lst[k - 1]) {
                float t2 = lst[k]; lst[k] = lst[k - 1]; lst[k - 1] = t2;
            }
    }
}

// k1: R15 shape, but DMA sources are strictly LINEAR (monotonic lane*16) —
// testing the theory that XOR-swizzled per-lane source addresses break TA
// sector coalescing (the invariant across all ~90-100us DMA variants).
// Bank conflicts handled by PADDED row stride (2064 B) instead of swizzle:
// b128 fragment reads become 4-way (1.58x, acceptable). Ring-3, depth-2
// prefetch, ONE barrier per chunk with vmcnt(2)+lgkmcnt(0) before it
// (ring distance makes DMA(c+2) WAR-safe post-barrier). Norms bt0-only.
__global__ __launch_bounds__(1024) void k1_sims(const float* __restrict__ t_f,
                                                const float* __restrict__ gal,
                                                float2* __restrict__ partial) {
    __shared__ __align__(16) char gbuf[3][CHR * RSTR];   // 99072 B ring
    __shared__ __align__(16) float cbuf_c[2][16][256];   // 32768 B C exchange
    __shared__ __align__(16) float cbuf_n[2][16][16];    //  2048 B norm exchange

    const int tid = threadIdx.x;
    const int blk = blockIdx.x;
    const int lane = tid & 63;
    const int w = tid >> 6;          // 0..15
    const int bt = w & 7;            // b-tile
    const int kh = w >> 3;           // k-half
    const int l15 = lane & 15;
    const int l4 = lane >> 4;

    const char* gal_b = reinterpret_cast<const char*>(gal);
    const size_t rowbase = (size_t)blk * GPB * 2048;

    // t-fragments first (their waits must not drain the DMA queue):
    // lane holds t[bt*16 + l15][ks*32 + l4*8 ..+8], ks = kh*8+j. 32 VGPR.
    short8 tfr[8];
    {
        const float* tp = t_f + (size_t)(bt * 16 + l15) * D + (kh * 8) * 32 + l4 * 8;
        #pragma unroll
        for (int j = 0; j < 8; ++j) {
            float4 a = *reinterpret_cast<const float4*>(tp + j * 32);
            float4 b = *reinterpret_cast<const float4*>(tp + j * 32 + 4);
            uint4 q;
            q.x = pack_bf2(a.x, a.y); q.y = pack_bf2(a.z, a.w);
            q.z = pack_bf2(b.x, b.y); q.w = pack_bf2(b.z, b.w);
            tfr[j] = *reinterpret_cast<short8*>(&q);
        }
    }
    __builtin_amdgcn_sched_barrier(0);

    // wave w stages row w of chunk c: 2 x 1KB contiguous, LINEAR source
#define DMA(c) do { \
        const char* s_ = gal_b + rowbase + ((size_t)(c) * CHR + w) * 2048 + lane * 16; \
        char* d_ = &gbuf[(c) % 3][w * RSTR]; \
        __builtin_amdgcn_global_load_lds((as1cu8*)s_, (as3u8*)d_, 16, 0, 0); \
        __builtin_amdgcn_global_load_lds((as1cu8*)(s_ + 1024), (as3u8*)(d_ + 1024), 16, 0, 0); \
    } while (0)

    DMA(0); DMA(1);   // depth-2: 4 ops/wave in flight

    float lst[K];
    #pragma unroll
    for (int k = 0; k < K; ++k) lst[k] = -1e30f;

    // compute chunk c (this wave's k-half): A = g-rows (row=l15), C row(g)=l4*4+r
#define COMPUTE(c) do { \
        f32x4 acc_ = (f32x4)0.0f; \
        float nrm_ = 0.0f; \
        const char* gb_ = &gbuf[(c) % 3][0] + l15 * RSTR; \
        _Pragma("unroll") \
        for (int j_ = 0; j_ < 8; ++j_) { \
            const int co_ = (kh * 8 + j_) * 128 + l4 * 32; \
            float4 a0_ = *reinterpret_cast<const float4*>(gb_ + co_); \
            float4 a1_ = *reinterpret_cast<const float4*>(gb_ + co_ + 16); \
            if (bt == 0) { \
                nrm_ = fmaf(a0_.x, a0_.x, nrm_); nrm_ = fmaf(a0_.y, a0_.y, nrm_); \
                nrm_ = fmaf(a0_.z, a0_.z, nrm_); nrm_ = fmaf(a0_.w, a0_.w, nrm_); \
                nrm_ = fmaf(a1_.x, a1_.x, nrm_); nrm_ = fmaf(a1_.y, a1_.y, nrm_); \
                nrm_ = fmaf(a1_.z, a1_.z, nrm_); nrm_ = fmaf(a1_.w, a1_.w, nrm_); \
            } \
            uint4 q_; \
            q_.x = pack_bf2(a0_.x, a0_.y); q_.y = pack_bf2(a0_.z, a0_.w); \
            q_.z = pack_bf2(a1_.x, a1_.y); q_.w = pack_bf2(a1_.z, a1_.w); \
            short8 af_ = *reinterpret_cast<short8*>(&q_); \
            acc_ = __builtin_amdgcn_mfma_f32_16x16x32_bf16(af_, tfr[j_], acc_, 0, 0, 0); \
        } \
        if (bt == 0) { \
            nrm_ += __shfl_xor(nrm_, 16); \
            nrm_ += __shfl_xor(nrm_, 32); \
            if (lane < CHR) cbuf_n[(c) & 1][kh * 8][lane] = nrm_; \
        } \
        *reinterpret_cast<f32x4*>(&cbuf_c[(c) & 1][w][lane * 4]) = acc_; \
    } while (0)

    // finish chunk c (kh==1 waves): sum k-halves, scale, top-5 insert
#define FINISH(c) do { \
        const int pb_ = (c) & 1; \
        f32x4 c0_ = *reinterpret_cast<const f32x4*>(&cbuf_c[pb_][bt][lane * 4]); \
        f32x4 c1_ = *reinterpret_cast<const f32x4*>(&cbuf_c[pb_][8 + bt][lane * 4]); \
        float4 n0_ = *reinterpret_cast<const float4*>(&cbuf_n[pb_][0][l4 * 4]); \
        float4 n1_ = *reinterpret_cast<const float4*>(&cbuf_n[pb_][8][l4 * 4]); \
        float nn_[4] = {n0_.x + n1_.x, n0_.y + n1_.y, n0_.z + n1_.z, n0_.w + n1_.w}; \
        _Pragma("unroll") \
        for (int r_ = 0; r_ < 4; ++r_) { \
            float s_ = (c0_[r_] + c1_[r_]) * rsqrtf(fmaxf(nn_[r_], 1e-24f)); \
            unsigned meta_ = (unsigned)((c) * CHR + l4 * 4 + r_); \
            float sp_ = __uint_as_float((__float_as_uint(s_) & 0xFFFFFF00u) | meta_); \
            pk_insert(sp_, lst); \
        } \
    } while (0)

    // one barrier per chunk; DMA(c+2) issued post-barrier is WAR-safe:
    // slot (c+2)%3 was last read in iter c-1, and every wave passed this
    // iteration's barrier only after finishing iter c-1's reads.
#define ITER(c, vmn) \
    asm volatile("s_waitcnt vmcnt(" #vmn ") lgkmcnt(0)" ::: "memory"); \
    __builtin_amdgcn_sched_barrier(0); \
    __builtin_amdgcn_s_barrier(); \
    __builtin_amdgcn_sched_barrier(0); \
    if ((c) + 2 < NCHK) DMA((c) + 2); \
    if ((c) > 0 && kh == 1) FINISH((c) - 1); \
    COMPUTE(c);

    ITER(0, 2)  ITER(1, 2)  ITER(2, 2)  ITER(3, 2)
    ITER(4, 2)  ITER(5, 2)  ITER(6, 2)  ITER(7, 2)
    ITER(8, 2)  ITER(9, 2)  ITER(10, 2) ITER(11, 2)
    ITER(12, 2) ITER(13, 2) ITER(14, 2) ITER(15, 0)

    // drain cbuf writes of chunk 15, then final FINISH
    asm volatile("s_waitcnt lgkmcnt(0)" ::: "memory");
    __builtin_amdgcn_sched_barrier(0);
    __builtin_amdgcn_s_barrier();
    __builtin_amdgcn_sched_barrier(0);

    if (kh == 1) {
        FINISH(15);
        // merge per-b lists across the 4 l4 lanes (same b = bt*16 + l15)
        #pragma unroll
        for (int mk = 16; mk <= 32; mk <<= 1) {
            float inc[K];
            #pragma unroll
            for (int k = 0; k < K; ++k) inc[k] = __shfl_xor(lst[k], mk);
            #pragma unroll
            for (int k = 0; k < K; ++k) pk_insert(inc[k], lst);
        }
        if (l4 == 0) {
            const int b = bt * 16 + l15;
            #pragma unroll
            for (int k = 0; k < K; ++k) {
                unsigned sp = __float_as_uint(lst[k]);
                int g = blk * GPB + (int)(sp & 0xFFu);
                partial[((size_t)b * NBLK1 + blk) * K + k] = make_float2(lst[k], __int_as_float(g));
            }
        }
    }
#undef ITER
#undef FINISH
#undef COMPUTE
#undef DMA
}

// k2: merge 256 partial top-5 lists per batch row -> top_idx. Shuffle-first.
__global__ __launch_bounds__(512) void k2_merge(const float2* __restrict__ partial,
                                                int* __restrict__ top_idx) {
    __shared__ float2 wlist[8][K];
    const int b = blockIdx.x;
    const int p = threadIdx.x;
    const int lane = p & 63;
    const int w = p >> 6;

    float mv[K]; int mi[K];
    #pragma unroll
    for (int k = 0; k < K; ++k) { mv[k] = -1e30f; mi[k] = 0x7fffffff; }
    if (p < NBLK1) {
        #pragma unroll
        for (int k = 0; k < K; ++k) {
            float2 c = partial[((size_t)b * NBLK1 + p) * K + k];
            mv[k] = c.x; mi[k] = __float_as_int(c.y);
        }
    }
    #pragma unroll
    for (int mk = 1; mk <= 32; mk <<= 1) {
        float ov[K]; int oi[K];
        #pragma unroll
        for (int k = 0; k < K; ++k) { ov[k] = __shfl_xor(mv[k], mk); oi[k] = __shfl_xor(mi[k], mk); }
        #pragma unroll
        for (int k = 0; k < K; ++k) top5_insert(ov[k], oi[k], mv, mi);
    }
    if (lane == 0) {
        #pragma unroll
        for (int k = 0; k < K; ++k) wlist[w][k] = make_float2(mv[k], __int_as_float(mi[k]));
    }
    __syncthreads();
    if (w == 0) {
        #pragma unroll
        for (int k = 0; k < K; ++k) { mv[k] = -1e30f; mi[k] = 0x7fffffff; }
        if (lane < 8) {
            #pragma unroll
            for (int k = 0; k < K; ++k) {
                float2 c = wlist[lane][k];
                mv[k] = c.x; mi[k] = __float_as_int(c.y);
            }
        }
        #pragma unroll
        for (int mk = 1; mk <= 4; mk <<= 1) {
            float ov[K]; int oi[K];
            #pragma unroll
            for (int k = 0; k < K; ++k) { ov[k] = __shfl_xor(mv[k], mk); oi[k] = __shfl_xor(mi[k], mk); }
            #pragma unroll
            for (int k = 0; k < K; ++k) top5_insert(ov[k], oi[k], mv, mi);
        }
        if (lane == 0) {
            #pragma unroll
            for (int k = 0; k < K; ++k) top_idx[b * K + k] = mi[k];
        }
    }
}

// k3: one block per (b,k) row: bottom-m membership of |gal[row,c]*s_f[b,c]|
// (per-row norms are positive constants -> ordering matches the reference's
// normalized products). Plain stores; kernel-boundary coherence (R8 lesson).
__global__ __launch_bounds__(512) void k3_member(const float* __restrict__ s_f,
                                                 const float* __restrict__ gal,
                                                 const int* __restrict__ top_idx,
                                                 unsigned long long* __restrict__ bkmask) {
    __shared__ __align__(16) float pS[D];
    const int p = threadIdx.x;
    const int bk = blockIdx.x;
    const int b = bk / K;
    const int row = top_idx[bk];
    float pv = fabsf(gal[(size_t)row * D + p] * s_f[(size_t)b * D + p]);
    pS[p] = pv;
    __syncthreads();
    int cnt = 0;
    const float4* p4 = reinterpret_cast<const float4*>(pS);
    #pragma unroll 4
    for (int j = 0; j < D / 4; ++j) {
        float4 o = p4[j];
        cnt += (o.x < pv || (o.x == pv && (4 * j + 0) < p)) ? 1 : 0;
        cnt += (o.y < pv || (o.y == pv && (4 * j + 1) < p)) ? 1 : 0;
        cnt += (o.z < pv || (o.z == pv && (4 * j + 2) < p)) ? 1 : 0;
        cnt += (o.w < pv || (o.w == pv && (4 * j + 3) < p)) ? 1 : 0;
    }
    unsigned long long bm = __ballot(cnt < M);
    if ((p & 63) == 0) bkmask[(size_t)bk * 8 + (p >> 6)] = bm;
}

// k4: AND-reduce the 640 per-(b,k) masks, emit the output mask. 40 KB, L2-hot.
__global__ __launch_bounds__(512) void k4_final(const unsigned long long* __restrict__ bkmask,
                                                float* __restrict__ out) {
    const int c = threadIdx.x;
    const int word = c >> 6, bit = c & 63;
    unsigned long long acc = ~0ull;
    for (int bk = 0; bk < B * K; bk += 4) {
        acc &= bkmask[(size_t)bk * 8 + word];
        acc &= bkmask[(size_t)(bk + 1) * 8 + word];
        acc &= bkmask[(size_t)(bk + 2) * 8 + word];
        acc &= bkmask[(size_t)(bk + 3) * 8 + word];
    }
    out[c] = ((acc >> bit) & 1ull) ? 0.0f : 1.0f;
}

extern "C" void kernel_launch(void* const* d_in, const int* in_sizes, int n_in,
                              void* d_out, int out_size, void* d_ws, size_t ws_size,
                              hipStream_t stream) {
    (void)in_sizes; (void)n_in; (void)out_size; (void)ws_size;
    const float* s_f = (const float*)d_in[0];
    const float* t_f = (const float*)d_in[1];
    const float* gal = (const float*)d_in[2];
    float* out = (float*)d_out;

    char* ws = (char*)d_ws;
    const size_t off_partial = 0;                        // 128*256*5*8 = 1310720
    const size_t off_topidx  = off_partial + 1310720;    // 2560
    const size_t off_bkmask  = off_topidx + 2560;        // 40960

    float2* partial = (float2*)(ws + off_partial);
    int* top_idx = (int*)(ws + off_topidx);
    unsigned long long* bkmask = (unsigned long long*)(ws + off_bkmask);

    hipLaunchKernelGGL(k1_sims, dim3(NBLK1), dim3(1024), 0, stream, t_f, gal, partial);
    hipLaunchKernelGGL(k2_merge, dim3(B), dim3(512), 0, stream, partial, top_idx);
    hipLaunchKernelGGL(k3_member, dim3(B * K), dim3(512), 0, stream, s_f, gal, top_idx, bkmask);
    hipLaunchKernelGGL(k4_final, dim3(1), dim3(512), 0, stream, bkmask, out);
}